// Round 3
// baseline (78.481 us; speedup 1.0000x reference)
//
#include <hip/hip_runtime.h>
#include <hip/hip_bf16.h>

#define N_ANCH 49104
#define NB 16
#define NGT 100
#define NC 80
#define BPI 96              // blocks per image
#define APB 512             // anchors per block (2 per thread)
#define NBLK (BPI * NB)     // 1536 total blocks

#define LOG2E 1.4426950408889634f
#define LN2   0.6931471805599453f

__device__ __forceinline__ float frcp(float x){ return __builtin_amdgcn_rcpf(x); }
__device__ __forceinline__ float fexp2(float x){ return __builtin_amdgcn_exp2f(x); }
__device__ __forceinline__ float flog2(float x){ return __builtin_amdgcn_logf(x); }

// acc += p(x)^2 * (softplus(x)/LN2)   [caller scales by 0.75*LN2]
// log-space, branchless: 9 VALU + 3 trans
__device__ __forceinline__ float f0_acc(float x, float acc){
  float xl = x * LOG2E;
  float mx = fmaxf(xl, 0.f);
  float mn = fminf(xl, 0.f);
  float u  = fexp2(mn - mx);      // e^{-|x|}
  float w  = 1.0f + u;
  float lw = flog2(w);
  float g  = mn - lw;             // log2(sigmoid(x))
  float p2 = fexp2(g + g);
  return fmaf(p2, lw + mx, acc);
}

// (f1 - f0) correction for the one-hot label class
__device__ __forceinline__ float corr_term(float x){
  float xl = x * LOG2E;
  float mx = fmaxf(xl, 0.f);
  float mn = fminf(xl, 0.f);
  float u  = fexp2(mn - mx);
  float w  = 1.0f + u;
  float lw = flog2(w);
  float p2   = fexp2(2.f * (mn - lw));     // sigmoid(x)^2
  float omp2 = fexp2(-2.f * (mx + lw));    // (1-sigmoid(x))^2
  float sp   = LN2 * (lw + mx);            // softplus(x)
  float spn  = LN2 * (lw - mn);            // softplus(-x)
  return 0.25f * omp2 * spn - 0.75f * p2 * sp;
}

struct __align__(16) Acc { float c, bbx; int p; };

__device__ __forceinline__ void process_anchor(
    int b, int a,
    const float* __restrict__ cls, const float* __restrict__ bbox,
    const float4* s_gt, const float* s_area, const int* s_label,
    float& accC, float& accB, int& posi)
{
  // ---- regenerate anchor a (RetinaNet grid) ----
  int f, lg, st, rel;
  if      (a < 36864){ f = 64; lg = 6; st = 8;   rel = a; }
  else if (a < 46080){ f = 32; lg = 5; st = 16;  rel = a - 36864; }
  else if (a < 48384){ f = 16; lg = 4; st = 32;  rel = a - 46080; }
  else if (a < 48960){ f = 8;  lg = 3; st = 64;  rel = a - 48384; }
  else               { f = 4;  lg = 2; st = 128; rel = a - 48960; }
  int cell = rel / 9;
  int k    = rel - cell * 9;
  int yy   = cell >> lg;
  int xx   = cell & (f - 1);
  int rr = (k >= 6) ? 2 : ((k >= 3) ? 1 : 0);
  int sc = k - rr * 3;
  double sq  = (rr == 0) ? 0.7071067811865476 : ((rr == 1) ? 1.0 : 1.4142135623730951);
  double scl = (sc == 0) ? 4.0 : ((sc == 1) ? 5.039684199579493 : 6.349604207872798);
  double ss  = (double)st * scl;
  double wd  = ss / sq, hd = ss * sq;
  double cxd = ((double)xx + 0.5) * (double)st;
  double cyd = ((double)yy + 0.5) * (double)st;
  float x1 = (float)(cxd - wd * 0.5);
  float y1 = (float)(cyd - hd * 0.5);
  float x2 = (float)(cxd + wd * 0.5);
  float y2 = (float)(cyd + hd * 0.5);
  float areaA = (x2 - x1) * (y2 - y1);

  // ---- IoU argmax (rcp on trans pipe; no clamp: U >= areaA > 0) ----
  float best_iou = -1.f; int best = 0;
  #pragma unroll 4
  for (int j = 0; j < NGT; ++j){
    float4 g = s_gt[j];
    float lx = fmaxf(x1, g.x), ly = fmaxf(y1, g.y);
    float rx = fminf(x2, g.z), ry = fminf(y2, g.w);
    float iw = fmaxf(rx - lx, 0.f), ih = fmaxf(ry - ly, 0.f);
    float I  = iw * ih;
    float U  = (areaA + s_area[j]) - I;
    float iou = I * frcp(U);
    best = (iou > best_iou) ? j : best;
    best_iou = fmaxf(iou, best_iou);
  }

  bool pos = best_iou >= 0.5f;
  bool ign = (!pos) && (best_iou >= 0.4f);

  if (pos){
    posi += 1;
    float4 g = s_gt[best];
    float aw = x2 - x1, ah = y2 - y1;
    float axc = (x1 + x2) * 0.5f, ayc = (y1 + y2) * 0.5f;
    float gw = fmaxf(g.z - g.x, 1e-6f), gh = fmaxf(g.w - g.y, 1e-6f);
    float gxc = (g.x + g.z) * 0.5f, gyc = (g.y + g.w) * 0.5f;
    float t0 = (gxc - axc) / aw, t1 = (gyc - ayc) / ah;
    float t2 = LN2 * flog2(gw * frcp(aw));
    float t3 = LN2 * flog2(gh * frcp(ah));
    float4 bp = ((const float4*)bbox)[(size_t)b * N_ANCH + a];
    const float BETA = 1.0f / 9.0f;
    float d0 = fabsf(bp.x - t0), d1 = fabsf(bp.y - t1);
    float d2 = fabsf(bp.z - t2), d3 = fabsf(bp.w - t3);
    accB += (d0 < BETA) ? 4.5f * d0 * d0 : d0 - 0.5f * BETA;
    accB += (d1 < BETA) ? 4.5f * d1 * d1 : d1 - 0.5f * BETA;
    accB += (d2 < BETA) ? 4.5f * d2 * d2 : d2 - 0.5f * BETA;
    accB += (d3 < BETA) ? 4.5f * d3 * d3 : d3 - 0.5f * BETA;
  }

  // ---- focal t=0 sum over all classes (4 independent accumulators) ----
  if (!ign){
    float a0 = 0.f, a1 = 0.f, a2 = 0.f, a3 = 0.f;
    const float4* cp = (const float4*)(cls + (size_t)(b * N_ANCH + a) * NC);
    #pragma unroll 4
    for (int v = 0; v < NC / 4; ++v){
      float4 c4 = cp[v];
      a0 = f0_acc(c4.x, a0);
      a1 = f0_acc(c4.y, a1);
      a2 = f0_acc(c4.z, a2);
      a3 = f0_acc(c4.w, a3);
    }
    accC += (0.75f * LN2) * ((a0 + a1) + (a2 + a3));
    if (pos){
      int label = s_label[best];
      float xl = cls[(size_t)(b * N_ANCH + a) * NC + label];   // L1 hit
      accC += corr_term(xl);
    }
  }
  // note: pos && ign are mutually exclusive; pos anchors always take the
  // focal path (ign false), matching mask_cls = (idx >= -1).
}

__global__ __launch_bounds__(256, 6) void anchor_loss_kernel(
    const float* __restrict__ cls,
    const float* __restrict__ bbox,
    const float* __restrict__ gtb,
    const int*   __restrict__ gtl,
    const unsigned char* __restrict__ gmask,
    float* __restrict__ ws)     // partials: c[NBLK], bb[NBLK], p[NBLK]
{
  const int tid = threadIdx.x;
  const int b   = blockIdx.y;
  const int base = blockIdx.x * APB;
  const int blk  = b * BPI + blockIdx.x;

  __shared__ float4 s_gt[NGT];
  __shared__ float  s_area[NGT];
  __shared__ int    s_label[NGT];
  __shared__ int    s_notfloat, s_offbyte;
  __shared__ float  s_rc[4], s_rb[4];
  __shared__ int    s_rp[4];

  if (tid == 0){ s_notfloat = 0; s_offbyte = 0; }
  __syncthreads();

  // ---- detect mask_labels storage layout (bool8 vs int32 vs float32) ----
  {
    const unsigned int* mw = (const unsigned int*)gmask;
    int nf = 0, ob = 0;
    for (int i = tid; i < (NB * NGT) / 4; i += 256){
      unsigned int w = mw[i];
      if (w != 0u && w != 0x3F800000u) nf = 1;
      if (w & 0xFFFFFF00u)             ob = 1;
    }
    if (nf) s_notfloat = 1;
    if (ob) s_offbyte  = 1;
  }
  __syncthreads();
  const bool byteLayout = (s_notfloat && s_offbyte);

  // ---- stage GT; invalid GTs -> degenerate far-away box (IoU == 0) ----
  for (int j = tid; j < NGT; j += 256){
    float4 g = ((const float4*)gtb)[b * NGT + j];
    int v;
    if (byteLayout) v = (gmask[b * NGT + j] != 0);
    else            v = (((const unsigned int*)gmask)[b * NGT + j] != 0u);
    if (!v){ g.x = 3e9f; g.y = 3e9f; g.z = 3e9f; g.w = 3e9f; }
    s_gt[j]    = g;
    s_area[j]  = (g.z - g.x) * (g.w - g.y);
    s_label[j] = gtl[b * NGT + j];
  }
  __syncthreads();

  float accC = 0.f, accB = 0.f;
  int posi = 0;

  // item 1: always valid (base+tid <= 48768+255 < 49104)
  process_anchor(b, base + tid, cls, bbox, s_gt, s_area, s_label, accC, accB, posi);
  // item 2: valid unless past image end (only tail of last block per image)
  int a1 = base + 256 + tid;
  if (a1 < N_ANCH && a1 < base + APB)
    process_anchor(b, a1, cls, bbox, s_gt, s_area, s_label, accC, accB, posi);

  // ---- block reduction ----
  #pragma unroll
  for (int o = 32; o > 0; o >>= 1){
    accC += __shfl_down(accC, o);
    accB += __shfl_down(accB, o);
    posi += __shfl_down(posi, o);
  }
  int wave = tid >> 6, lane = tid & 63;
  if (lane == 0){ s_rc[wave] = accC; s_rb[wave] = accB; s_rp[wave] = posi; }
  __syncthreads();
  if (tid == 0){
    ws[blk]            = s_rc[0] + s_rc[1] + s_rc[2] + s_rc[3];
    ws[NBLK + blk]     = s_rb[0] + s_rb[1] + s_rb[2] + s_rb[3];
    ws[2 * NBLK + blk] = (float)(s_rp[0] + s_rp[1] + s_rp[2] + s_rp[3]);
  }
}

__global__ void finalize_kernel(const float* __restrict__ ws,
                                float* __restrict__ out)
{
  __shared__ float sC[NB], sB[NB];
  const int tid = threadIdx.x;          // 512 threads = 8 waves
  const int wv = tid >> 6, ln = tid & 63;
  #pragma unroll
  for (int i = 0; i < 2; ++i){
    int b = wv * 2 + i;
    int base = b * BPI;
    float c = ws[base + ln];                    // ln < 64 < BPI=96
    float bb = ws[NBLK + base + ln];
    float p  = ws[2 * NBLK + base + ln];
    if (ln + 64 < BPI){
      c  += ws[base + 64 + ln];
      bb += ws[NBLK + base + 64 + ln];
      p  += ws[2 * NBLK + base + 64 + ln];
    }
    #pragma unroll
    for (int o = 32; o > 0; o >>= 1){
      c += __shfl_down(c, o); bb += __shfl_down(bb, o); p += __shfl_down(p, o);
    }
    if (ln == 0){
      float tot = fmaxf(p, 1.f);
      sC[b] = c / tot;
      sB[b] = bb / tot;
    }
  }
  __syncthreads();
  if (tid == 0){
    float lc = 0.f, lb = 0.f;
    #pragma unroll
    for (int b = 0; b < NB; ++b){ lc += sC[b]; lb += sB[b]; }
    out[0] = lc / 16.f;
    out[1] = 10.f * lb / 16.f;
  }
}

extern "C" void kernel_launch(void* const* d_in, const int* in_sizes, int n_in,
                              void* d_out, int out_size, void* d_ws, size_t ws_size,
                              hipStream_t stream) {
  const float* cls  = (const float*)d_in[0];
  const float* bbox = (const float*)d_in[1];
  const float* gtb  = (const float*)d_in[2];
  const int*   gtl  = (const int*)d_in[3];
  const unsigned char* gmask = (const unsigned char*)d_in[4];

  float* ws = (float*)d_ws;   // 3*NBLK floats, fully overwritten every call

  dim3 grid(BPI, NB);
  anchor_loss_kernel<<<grid, 256, 0, stream>>>(cls, bbox, gtb, gtl, gmask, ws);
  finalize_kernel<<<1, 512, 0, stream>>>(ws, (float*)d_out);
}

// Round 4
// 65.418 us; speedup vs baseline: 1.1997x; 1.1997x over previous
//
#include <hip/hip_runtime.h>

#define N_ANCH 49104
#define NB_IMG 16
#define NGT 100
#define NC 80
#define BPIA 128                   // phase-A blocks per image
#define BPIB 192                   // phase-B blocks per image (256 anchors each)
#define NA_BLK (BPIA * NB_IMG)     // 2048
#define NB_BLK (BPIB * NB_IMG)     // 3072
#define IMG_F4 (N_ANCH * NC / 4)   // 982080 float4 per image
#define OFF_C NA_BLK
#define OFF_B (NA_BLK + NB_BLK)
#define OFF_P (NA_BLK + 2 * NB_BLK)

#define LOG2E 1.4426950408889634f
#define LN2   0.6931471805599453f
#define FSCALE (0.75f * LN2)

__device__ __forceinline__ float frcp(float x){ return __builtin_amdgcn_rcpf(x); }
__device__ __forceinline__ float fexp2(float x){ return __builtin_amdgcn_exp2f(x); }
__device__ __forceinline__ float flog2(float x){ return __builtin_amdgcn_logf(x); }

// acc += p(x)^2 * softplus(x)/LN2   (dimensionless; caller scales by 0.75*LN2)
__device__ __forceinline__ float f0_acc(float x, float acc){
  float xl = x * LOG2E;
  float mx = fmaxf(xl, 0.f);
  float mn = fminf(xl, 0.f);
  float u  = fexp2(mn - mx);      // e^{-|x|}
  float w  = 1.0f + u;
  float lw = flog2(w);
  float g  = mn - lw;             // log2(sigmoid)
  float p2 = fexp2(g + g);
  return fmaf(p2, lw + mx, acc);
}

// (f1 - f0) correction for the one-hot label class (absolute units)
__device__ __forceinline__ float corr_term(float x){
  float xl = x * LOG2E;
  float mx = fmaxf(xl, 0.f);
  float mn = fminf(xl, 0.f);
  float u  = fexp2(mn - mx);
  float w  = 1.0f + u;
  float lw = flog2(w);
  float p2   = fexp2(2.f * (mn - lw));
  float omp2 = fexp2(-2.f * (mx + lw));
  float sp   = LN2 * (lw + mx);
  float spn  = LN2 * (lw - mn);
  return 0.25f * omp2 * spn - 0.75f * p2 * sp;
}

__global__ __launch_bounds__(256, 6) void fused_loss_kernel(
    const float* __restrict__ cls,
    const float* __restrict__ bbox,
    const float* __restrict__ gtb,
    const int*   __restrict__ gtl,
    const unsigned char* __restrict__ gmask,
    float* __restrict__ ws)
{
  const int tid = threadIdx.x;
  const int wv = tid >> 6, ln = tid & 63;

  __shared__ float  s_r0[4], s_r1[4], s_r2[4];
  __shared__ float  s_wmin[4], s_wmax[4];
  __shared__ float4 s_cgt[NGT + 4];
  __shared__ float  s_carea[NGT + 4];
  __shared__ int    s_clab[NGT + 4];
  __shared__ int    s_cnt;

  const int idx = blockIdx.x;
  const int role = idx % 5;

  if (role < 2){
    // ================= PHASE A: coalesced f0 stream over cls =================
    int aid = (idx / 5) * 2 + role;
    int b = aid / BPIA, s = aid % BPIA;
    const float4* p = (const float4*)cls + (size_t)b * IMG_F4;
    float a0 = 0.f, a1 = 0.f, a2 = 0.f, a3 = 0.f;
    #pragma unroll 2
    for (int i = s * 256 + tid; i < IMG_F4; i += BPIA * 256){
      float4 c4 = p[i];
      a0 = f0_acc(c4.x, a0); a1 = f0_acc(c4.y, a1);
      a2 = f0_acc(c4.z, a2); a3 = f0_acc(c4.w, a3);
    }
    float acc = (a0 + a1) + (a2 + a3);
    #pragma unroll
    for (int o = 32; o > 0; o >>= 1) acc += __shfl_down(acc, o);
    if (ln == 0) s_r0[wv] = acc;
    __syncthreads();
    if (tid == 0) ws[aid] = s_r0[0] + s_r0[1] + s_r0[2] + s_r0[3];
    return;
  }

  // ================= PHASE B: assignment (1 anchor / thread) =================
  int bid = (idx / 5) * 3 + (role - 2);
  int b = bid / BPIB, blkc = bid % BPIB;
  int a = blkc * 256 + tid;
  bool va = a < N_ANCH;

  // ---- anchor geometry (f64 to match numpy anchor gen) ----
  float x1, y1, x2, y2, areaA;
  if (va){
    int f, lg, st, rel;
    if      (a < 36864){ f = 64; lg = 6; st = 8;   rel = a; }
    else if (a < 46080){ f = 32; lg = 5; st = 16;  rel = a - 36864; }
    else if (a < 48384){ f = 16; lg = 4; st = 32;  rel = a - 46080; }
    else if (a < 48960){ f = 8;  lg = 3; st = 64;  rel = a - 48384; }
    else               { f = 4;  lg = 2; st = 128; rel = a - 48960; }
    int cell = rel / 9;
    int k    = rel - cell * 9;
    int yy   = cell >> lg;
    int xx   = cell & (f - 1);
    int rr = (k >= 6) ? 2 : ((k >= 3) ? 1 : 0);
    int sc = k - rr * 3;
    double sq  = (rr == 0) ? 0.7071067811865476 : ((rr == 1) ? 1.0 : 1.4142135623730951);
    double scl = (sc == 0) ? 4.0 : ((sc == 1) ? 5.039684199579493 : 6.349604207872798);
    double ss  = (double)st * scl;
    double wd  = ss / sq, hd = ss * sq;
    double cxd = ((double)xx + 0.5) * (double)st;
    double cyd = ((double)yy + 0.5) * (double)st;
    x1 = (float)(cxd - wd * 0.5);
    y1 = (float)(cyd - hd * 0.5);
    x2 = (float)(cxd + wd * 0.5);
    y2 = (float)(cyd + hd * 0.5);
    areaA = (x2 - x1) * (y2 - y1);
  } else { x1 = 0.f; y1 = 3.0e38f; x2 = 0.f; y2 = -3.0e38f; areaA = 1.f; }

  // ---- block y-extent (exact; neutral values for invalid threads) ----
  {
    float wy1 = y1, wy2 = y2;
    #pragma unroll
    for (int o = 32; o > 0; o >>= 1){
      wy1 = fminf(wy1, __shfl_down(wy1, o));
      wy2 = fmaxf(wy2, __shfl_down(wy2, o));
    }
    if (ln == 0){ s_wmin[wv] = wy1; s_wmax[wv] = wy2; }
  }
  __syncthreads();

  if (wv == 0){
    // mask layout detection (bool8 vs int32 vs float32), wave-local
    const unsigned int* mw = (const unsigned int*)gmask;
    bool nf = false, ob = false;
    for (int i = ln; i < (NB_IMG * NGT) / 4; i += 64){
      unsigned int w = mw[i];
      nf |= (w != 0u && w != 0x3F800000u);
      ob |= ((w & 0xFFFFFF00u) != 0u);
    }
    bool byteLayout = __any((int)nf) && __any((int)ob);
    float ymin = fminf(fminf(s_wmin[0], s_wmin[1]), fminf(s_wmin[2], s_wmin[3]));
    float ymax = fmaxf(fmaxf(s_wmax[0], s_wmax[1]), fmaxf(s_wmax[2], s_wmax[3]));
    const float4* g4 = (const float4*)gtb;

    // chunk 0: GT j = ln (0..63); invalid GTs fail filter naturally
    float4 g = g4[b * NGT + ln];
    int v = byteLayout ? (gmask[b * NGT + ln] != 0)
                       : (((const unsigned int*)gmask)[b * NGT + ln] != 0u);
    bool pass = v && (g.y < ymax) && (g.w > ymin);     // y-overlap possible
    unsigned long long bal = __ballot(pass);
    int pre = __popcll(bal & ((1ull << ln) - 1ull));
    if (pass){
      s_cgt[pre] = g;
      s_carea[pre] = (g.z - g.x) * (g.w - g.y);
      s_clab[pre] = gtl[b * NGT + ln];
    }
    int c0 = __popcll(bal);
    // chunk 1: GT j = 64+ln (ln < 36)
    bool pass1 = false; float4 g1;
    if (ln < NGT - 64){
      g1 = g4[b * NGT + 64 + ln];
      int v1 = byteLayout ? (gmask[b * NGT + 64 + ln] != 0)
                          : (((const unsigned int*)gmask)[b * NGT + 64 + ln] != 0u);
      pass1 = v1 && (g1.y < ymax) && (g1.w > ymin);
    }
    unsigned long long bal1 = __ballot(pass1);
    int pre1 = c0 + __popcll(bal1 & ((1ull << ln) - 1ull));
    if (pass1){
      s_cgt[pre1] = g1;
      s_carea[pre1] = (g1.z - g1.x) * (g1.w - g1.y);
      s_clab[pre1] = gtl[b * NGT + 64 + ln];
    }
    if (ln == 0){
      int cnt = c0 + __popcll(bal1);
      float4 far4; far4.x = 3e9f; far4.y = 3e9f; far4.z = 3e9f; far4.w = 3e9f;
      s_cgt[cnt] = far4;     s_carea[cnt] = 0.f;     s_clab[cnt] = 0;
      s_cgt[cnt + 1] = far4; s_carea[cnt + 1] = 0.f; s_clab[cnt + 1] = 0;
      s_cnt = (cnt + 1) & ~1;    // pad to even for unroll-2
    }
  }
  __syncthreads();

  float accC = 0.f, accB = 0.f, posf = 0.f;
  if (va){
    const int cntp = s_cnt;
    float best_iou = -1.f; int best = 0;
    for (int j = 0; j < cntp; j += 2){
      #pragma unroll
      for (int u2 = 0; u2 < 2; ++u2){
        int jj = j + u2;
        float4 g = s_cgt[jj];
        float lx = fmaxf(x1, g.x), ly = fmaxf(y1, g.y);
        float rx = fminf(x2, g.z), ry = fminf(y2, g.w);
        float iw = fmaxf(rx - lx, 0.f), ih = fmaxf(ry - ly, 0.f);
        float I  = iw * ih;
        float U  = (areaA + s_carea[jj]) - I;
        float iou = I * frcp(U);
        best = (iou > best_iou) ? jj : best;
        best_iou = fmaxf(iou, best_iou);
      }
    }
    bool pos = best_iou >= 0.5f;
    bool ign = (!pos) && (best_iou >= 0.4f);
    size_t row = (size_t)(b * N_ANCH + a) * NC;

    if (pos){
      posf = 1.f;
      float4 g = s_cgt[best];
      float aw = x2 - x1, ah = y2 - y1;
      float axc = (x1 + x2) * 0.5f, ayc = (y1 + y2) * 0.5f;
      float gw = fmaxf(g.z - g.x, 1e-6f), gh = fmaxf(g.w - g.y, 1e-6f);
      float gxc = (g.x + g.z) * 0.5f, gyc = (g.y + g.w) * 0.5f;
      float t0 = (gxc - axc) / aw, t1 = (gyc - ayc) / ah;
      float t2 = LN2 * flog2(gw * frcp(aw));
      float t3 = LN2 * flog2(gh * frcp(ah));
      float4 bp = ((const float4*)bbox)[(size_t)b * N_ANCH + a];
      const float BETA = 1.0f / 9.0f;
      float d0 = fabsf(bp.x - t0), d1 = fabsf(bp.y - t1);
      float d2 = fabsf(bp.z - t2), d3 = fabsf(bp.w - t3);
      accB += (d0 < BETA) ? 4.5f * d0 * d0 : d0 - 0.5f * BETA;
      accB += (d1 < BETA) ? 4.5f * d1 * d1 : d1 - 0.5f * BETA;
      accB += (d2 < BETA) ? 4.5f * d2 * d2 : d2 - 0.5f * BETA;
      accB += (d3 < BETA) ? 4.5f * d3 * d3 : d3 - 0.5f * BETA;
      accC += corr_term(cls[row + s_clab[best]]);   // (f1-f0) at label
    }
    if (ign){
      // subtract this row's f0 sum (phase A counted it; ignored rows excluded)
      const float4* cp = (const float4*)(cls + row);
      float i0 = 0.f, i1 = 0.f, i2 = 0.f, i3 = 0.f;
      #pragma unroll 4
      for (int v2 = 0; v2 < NC / 4; ++v2){
        float4 c4 = cp[v2];
        i0 = f0_acc(c4.x, i0); i1 = f0_acc(c4.y, i1);
        i2 = f0_acc(c4.z, i2); i3 = f0_acc(c4.w, i3);
      }
      accC -= FSCALE * ((i0 + i1) + (i2 + i3));
    }
  }

  #pragma unroll
  for (int o = 32; o > 0; o >>= 1){
    accC += __shfl_down(accC, o);
    accB += __shfl_down(accB, o);
    posf += __shfl_down(posf, o);
  }
  if (ln == 0){ s_r0[wv] = accC; s_r1[wv] = accB; s_r2[wv] = posf; }
  __syncthreads();
  if (tid == 0){
    ws[OFF_C + bid] = s_r0[0] + s_r0[1] + s_r0[2] + s_r0[3];
    ws[OFF_B + bid] = s_r1[0] + s_r1[1] + s_r1[2] + s_r1[3];
    ws[OFF_P + bid] = s_r2[0] + s_r2[1] + s_r2[2] + s_r2[3];
  }
}

__global__ void finalize_kernel(const float* __restrict__ ws,
                                float* __restrict__ out)
{
  __shared__ float sC[NB_IMG], sB[NB_IMG];
  const int tid = threadIdx.x;          // 512 threads = 8 waves
  const int wv = tid >> 6, ln = tid & 63;
  #pragma unroll
  for (int i = 0; i < 2; ++i){
    int b = wv * 2 + i;
    float sa = 0.f;
    for (int k = ln; k < BPIA; k += 64) sa += ws[b * BPIA + k];
    float c = 0.f, bb = 0.f, p = 0.f;
    for (int k = ln; k < BPIB; k += 64){
      c  += ws[OFF_C + b * BPIB + k];
      bb += ws[OFF_B + b * BPIB + k];
      p  += ws[OFF_P + b * BPIB + k];
    }
    c += FSCALE * sa;   // scale phase-A partial (linear, per-lane ok)
    #pragma unroll
    for (int o = 32; o > 0; o >>= 1){
      c += __shfl_down(c, o); bb += __shfl_down(bb, o); p += __shfl_down(p, o);
    }
    if (ln == 0){
      float tot = fmaxf(p, 1.f);
      sC[b] = c / tot;
      sB[b] = bb / tot;
    }
  }
  __syncthreads();
  if (tid == 0){
    float lc = 0.f, lb = 0.f;
    #pragma unroll
    for (int b = 0; b < NB_IMG; ++b){ lc += sC[b]; lb += sB[b]; }
    out[0] = lc / 16.f;
    out[1] = 10.f * lb / 16.f;
  }
}

extern "C" void kernel_launch(void* const* d_in, const int* in_sizes, int n_in,
                              void* d_out, int out_size, void* d_ws, size_t ws_size,
                              hipStream_t stream) {
  const float* cls  = (const float*)d_in[0];
  const float* bbox = (const float*)d_in[1];
  const float* gtb  = (const float*)d_in[2];
  const int*   gtl  = (const int*)d_in[3];
  const unsigned char* gmask = (const unsigned char*)d_in[4];

  float* ws = (float*)d_ws;   // NA_BLK + 3*NB_BLK floats, fully overwritten

  int total_blocks = (NA_BLK + NB_BLK) / 5 * 5;   // 5120 (2A:3B interleave)
  fused_loss_kernel<<<total_blocks, 256, 0, stream>>>(cls, bbox, gtb, gtl, gmask, ws);
  finalize_kernel<<<1, 512, 0, stream>>>(ws, (float*)d_out);
}

// Round 5
// 57.247 us; speedup vs baseline: 1.3709x; 1.1427x over previous
//
#include <hip/hip_runtime.h>

#define N_ANCH 49104
#define NB_IMG 16
#define NGT 100
#define NC 80
#define BPI 96                 // blocks per image
#define APB 512                // anchors per block (2 per thread)
#define NBLK (BPI * NB_IMG)    // 1536
#define OFF_B NBLK
#define OFF_P (2 * NBLK)

#define LOG2E 1.4426950408889634f
#define LN2   0.6931471805599453f
#define FSCALE (0.75f * LN2)

__device__ __forceinline__ float frcp(float x){ return __builtin_amdgcn_rcpf(x); }
__device__ __forceinline__ float fexp2(float x){ return __builtin_amdgcn_exp2f(x); }
__device__ __forceinline__ float flog2(float x){ return __builtin_amdgcn_logf(x); }

// p(x)^2 * softplus(x)/LN2  (caller scales by 0.75*LN2)
__device__ __forceinline__ float f0_term(float x){
  float xl = x * LOG2E;
  float mx = fmaxf(xl, 0.f);
  float mn = fminf(xl, 0.f);
  float u  = fexp2(mn - mx);      // e^{-|x|}
  float w  = 1.0f + u;
  float lw = flog2(w);
  float g  = mn - lw;             // log2(sigmoid)
  return fexp2(g + g) * (lw + mx);
}

// (f1 - f0) correction for the one-hot label class (absolute units)
__device__ __forceinline__ float corr_term(float x){
  float xl = x * LOG2E;
  float mx = fmaxf(xl, 0.f);
  float mn = fminf(xl, 0.f);
  float u  = fexp2(mn - mx);
  float w  = 1.0f + u;
  float lw = flog2(w);
  float p2   = fexp2(2.f * (mn - lw));
  float omp2 = fexp2(-2.f * (mx + lw));
  float sp   = LN2 * (lw + mx);
  float spn  = LN2 * (lw - mn);
  return 0.25f * omp2 * spn - 0.75f * p2 * sp;
}

__global__ __launch_bounds__(256, 6) void fused_loss_kernel(
    const float* __restrict__ cls,
    const float* __restrict__ bbox,
    const float* __restrict__ gtb,
    const int*   __restrict__ gtl,
    const unsigned char* __restrict__ gmask,
    float* __restrict__ ws)
{
  const int tid = threadIdx.x;
  const int wv = tid >> 6, ln = tid & 63;
  const int b  = blockIdx.y;
  const int a0 = blockIdx.x * APB;
  const int bid = b * BPI + blockIdx.x;

  __shared__ float4 s_cgt[NGT + 4];
  __shared__ float  s_carea[NGT + 4];
  __shared__ int    s_clab[NGT + 4];
  __shared__ float  s_w[APB];          // row weight: 1 = pos|neg, 0 = ign|invalid
  __shared__ int    s_lab[APB];        // pos label or -1
  __shared__ float  s_wmin[4], s_wmax[4];
  __shared__ float  s_r0[4], s_r1[4], s_r2[4];
  __shared__ int    s_cnt;

  // ---- per-thread geometry for its 2 anchors (f64 matches numpy gen) ----
  float ax1[2], ay1[2], ax2[2], ay2[2], aarea[2];
  #pragma unroll
  for (int r = 0; r < 2; ++r){
    int a = a0 + r * 256 + tid;
    if (a < N_ANCH){
      int f, lg, st, rel;
      if      (a < 36864){ f = 64; lg = 6; st = 8;   rel = a; }
      else if (a < 46080){ f = 32; lg = 5; st = 16;  rel = a - 36864; }
      else if (a < 48384){ f = 16; lg = 4; st = 32;  rel = a - 46080; }
      else if (a < 48960){ f = 8;  lg = 3; st = 64;  rel = a - 48384; }
      else               { f = 4;  lg = 2; st = 128; rel = a - 48960; }
      int cell = rel / 9;
      int k    = rel - cell * 9;
      int yy   = cell >> lg;
      int xx   = cell & (f - 1);
      int rr = (k >= 6) ? 2 : ((k >= 3) ? 1 : 0);
      int sc = k - rr * 3;
      double sq  = (rr == 0) ? 0.7071067811865476 : ((rr == 1) ? 1.0 : 1.4142135623730951);
      double scl = (sc == 0) ? 4.0 : ((sc == 1) ? 5.039684199579493 : 6.349604207872798);
      double ss  = (double)st * scl;
      double wd  = ss / sq, hd = ss * sq;
      double cxd = ((double)xx + 0.5) * (double)st;
      double cyd = ((double)yy + 0.5) * (double)st;
      ax1[r] = (float)(cxd - wd * 0.5);
      ay1[r] = (float)(cyd - hd * 0.5);
      ax2[r] = (float)(cxd + wd * 0.5);
      ay2[r] = (float)(cyd + hd * 0.5);
      aarea[r] = (ax2[r] - ax1[r]) * (ay2[r] - ay1[r]);
    } else {
      ax1[r] = 0.f; ay1[r] = 3.0e38f; ax2[r] = 0.f; ay2[r] = -3.0e38f; aarea[r] = 1.f;
    }
  }

  // ---- block y-extent for GT prefilter ----
  {
    float wy1 = fminf(ay1[0], ay1[1]);
    float wy2 = fmaxf(ay2[0], ay2[1]);
    #pragma unroll
    for (int o = 32; o > 0; o >>= 1){
      wy1 = fminf(wy1, __shfl_down(wy1, o));
      wy2 = fmaxf(wy2, __shfl_down(wy2, o));
    }
    if (ln == 0){ s_wmin[wv] = wy1; s_wmax[wv] = wy2; }
  }
  __syncthreads();

  if (wv == 0){
    // mask layout detection (bool8 vs int32 vs float32), wave-local
    const unsigned int* mw = (const unsigned int*)gmask;
    bool nf = false, ob = false;
    for (int i = ln; i < (NB_IMG * NGT) / 4; i += 64){
      unsigned int w = mw[i];
      nf |= (w != 0u && w != 0x3F800000u);
      ob |= ((w & 0xFFFFFF00u) != 0u);
    }
    bool byteLayout = __any((int)nf) && __any((int)ob);
    float ymin = fminf(fminf(s_wmin[0], s_wmin[1]), fminf(s_wmin[2], s_wmin[3]));
    float ymax = fmaxf(fmaxf(s_wmax[0], s_wmax[1]), fmaxf(s_wmax[2], s_wmax[3]));
    const float4* g4 = (const float4*)gtb;

    // chunk 0: GT j = ln (0..63)
    float4 g = g4[b * NGT + ln];
    int v = byteLayout ? (gmask[b * NGT + ln] != 0)
                       : (((const unsigned int*)gmask)[b * NGT + ln] != 0u);
    bool pass = v && (g.y < ymax) && (g.w > ymin);   // exact: fails => IoU == 0
    unsigned long long bal = __ballot(pass);
    int pre = __popcll(bal & ((1ull << ln) - 1ull));
    if (pass){
      s_cgt[pre] = g;
      s_carea[pre] = (g.z - g.x) * (g.w - g.y);
      s_clab[pre] = gtl[b * NGT + ln];
    }
    int c0 = __popcll(bal);
    // chunk 1: GT j = 64+ln (ln < 36)
    bool pass1 = false; float4 g1;
    if (ln < NGT - 64){
      g1 = g4[b * NGT + 64 + ln];
      int v1 = byteLayout ? (gmask[b * NGT + 64 + ln] != 0)
                          : (((const unsigned int*)gmask)[b * NGT + 64 + ln] != 0u);
      pass1 = v1 && (g1.y < ymax) && (g1.w > ymin);
    }
    unsigned long long bal1 = __ballot(pass1);
    int pre1 = c0 + __popcll(bal1 & ((1ull << ln) - 1ull));
    if (pass1){
      s_cgt[pre1] = g1;
      s_carea[pre1] = (g1.z - g1.x) * (g1.w - g1.y);
      s_clab[pre1] = gtl[b * NGT + 64 + ln];
    }
    if (ln == 0){
      int cnt = c0 + __popcll(bal1);
      float4 far4; far4.x = 3e9f; far4.y = 3e9f; far4.z = 3e9f; far4.w = 3e9f;
      s_cgt[cnt] = far4;     s_carea[cnt] = 0.f;     s_clab[cnt] = 0;
      s_cgt[cnt + 1] = far4; s_carea[cnt + 1] = 0.f; s_clab[cnt + 1] = 0;
      s_cnt = (cnt + 1) & ~1;   // pad to even
    }
  }
  __syncthreads();

  // ---- assignment: IoU argmax for the thread's 2 anchors ----
  float accB = 0.f, posf = 0.f, fcorr = 0.f;
  const int cntp = s_cnt;
  #pragma unroll
  for (int r = 0; r < 2; ++r){
    int row = r * 256 + tid;
    int a = a0 + row;
    float x1 = ax1[r], y1 = ay1[r], x2 = ax2[r], y2 = ay2[r], areaA = aarea[r];
    float best_iou = -1.f; int best = 0;
    for (int j = 0; j < cntp; j += 2){
      #pragma unroll
      for (int u2 = 0; u2 < 2; ++u2){
        int jj = j + u2;
        float4 g = s_cgt[jj];
        float lx = fmaxf(x1, g.x), ly = fmaxf(y1, g.y);
        float rx = fminf(x2, g.z), ry = fminf(y2, g.w);
        float iw = fmaxf(rx - lx, 0.f), ih = fmaxf(ry - ly, 0.f);
        float I  = iw * ih;
        float U  = (areaA + s_carea[jj]) - I;
        float iou = I * frcp(U);
        best = (iou > best_iou) ? jj : best;
        best_iou = fmaxf(iou, best_iou);
      }
    }
    bool va  = a < N_ANCH;
    bool pos = va && (best_iou >= 0.5f);
    bool ign = va && !pos && (best_iou >= 0.4f);
    s_w[row]   = (va && !ign) ? 1.f : 0.f;
    s_lab[row] = pos ? s_clab[best] : -1;

    if (pos){
      posf += 1.f;
      float4 g = s_cgt[best];
      float aw = x2 - x1, ah = y2 - y1;
      float axc = (x1 + x2) * 0.5f, ayc = (y1 + y2) * 0.5f;
      float gw = fmaxf(g.z - g.x, 1e-6f), gh = fmaxf(g.w - g.y, 1e-6f);
      float gxc = (g.x + g.z) * 0.5f, gyc = (g.y + g.w) * 0.5f;
      float t0 = (gxc - axc) / aw, t1 = (gyc - ayc) / ah;
      float t2 = LN2 * flog2(gw * frcp(aw));
      float t3 = LN2 * flog2(gh * frcp(ah));
      float4 bp = ((const float4*)bbox)[(size_t)b * N_ANCH + a];
      const float BETA = 1.0f / 9.0f;
      float d0 = fabsf(bp.x - t0), d1 = fabsf(bp.y - t1);
      float d2 = fabsf(bp.z - t2), d3 = fabsf(bp.w - t3);
      accB += (d0 < BETA) ? 4.5f * d0 * d0 : d0 - 0.5f * BETA;
      accB += (d1 < BETA) ? 4.5f * d1 * d1 : d1 - 0.5f * BETA;
      accB += (d2 < BETA) ? 4.5f * d2 * d2 : d2 - 0.5f * BETA;
      accB += (d3 < BETA) ? 4.5f * d3 * d3 : d3 - 0.5f * BETA;
    }
  }
  __syncthreads();

  // ---- coalesced f0 stream over this block's own cls chunk ----
  // rows = anchors [a0, a0+nvalid); 20 float4 per row
  const int nvalid = min(N_ANCH - a0, APB);
  const int nf4 = nvalid * 20;
  const float4* cp = (const float4*)(cls + (size_t)(b * N_ANCH + a0) * NC);
  float fraw = 0.f;
  for (int i = tid; i < nf4; i += 256){
    float4 c4 = cp[i];
    int row = i / 20;                 // const-div -> mul/shift
    int cb  = (i - row * 20) * 4;     // first class of this float4
    float s = (f0_term(c4.x) + f0_term(c4.y)) + (f0_term(c4.z) + f0_term(c4.w));
    fraw = fmaf(s_w[row], s, fraw);
    int lab = s_lab[row];
    if ((unsigned)(lab - cb) < 4u){   // lab in [cb, cb+4); lab=-1 never hits
      int o = lab - cb;
      float xe = (o == 0) ? c4.x : (o == 1) ? c4.y : (o == 2) ? c4.z : c4.w;
      fcorr += corr_term(xe);
    }
  }
  float accC = fmaf(FSCALE, fraw, fcorr);

  // ---- block reduction ----
  #pragma unroll
  for (int o = 32; o > 0; o >>= 1){
    accC += __shfl_down(accC, o);
    accB += __shfl_down(accB, o);
    posf += __shfl_down(posf, o);
  }
  if (ln == 0){ s_r0[wv] = accC; s_r1[wv] = accB; s_r2[wv] = posf; }
  __syncthreads();
  if (tid == 0){
    ws[bid]         = s_r0[0] + s_r0[1] + s_r0[2] + s_r0[3];
    ws[OFF_B + bid] = s_r1[0] + s_r1[1] + s_r1[2] + s_r1[3];
    ws[OFF_P + bid] = s_r2[0] + s_r2[1] + s_r2[2] + s_r2[3];
  }
}

__global__ void finalize_kernel(const float* __restrict__ ws,
                                float* __restrict__ out)
{
  __shared__ float sC[NB_IMG], sB[NB_IMG];
  const int tid = threadIdx.x;          // 512 threads = 8 waves
  const int wv = tid >> 6, ln = tid & 63;
  #pragma unroll
  for (int i = 0; i < 2; ++i){
    int b = wv * 2 + i;
    float c = 0.f, bb = 0.f, p = 0.f;
    for (int k = ln; k < BPI; k += 64){
      c  += ws[b * BPI + k];
      bb += ws[OFF_B + b * BPI + k];
      p  += ws[OFF_P + b * BPI + k];
    }
    #pragma unroll
    for (int o = 32; o > 0; o >>= 1){
      c += __shfl_down(c, o); bb += __shfl_down(bb, o); p += __shfl_down(p, o);
    }
    if (ln == 0){
      float tot = fmaxf(p, 1.f);
      sC[b] = c / tot;
      sB[b] = bb / tot;
    }
  }
  __syncthreads();
  if (tid == 0){
    float lc = 0.f, lb = 0.f;
    #pragma unroll
    for (int b = 0; b < NB_IMG; ++b){ lc += sC[b]; lb += sB[b]; }
    out[0] = lc / 16.f;
    out[1] = 10.f * lb / 16.f;
  }
}

extern "C" void kernel_launch(void* const* d_in, const int* in_sizes, int n_in,
                              void* d_out, int out_size, void* d_ws, size_t ws_size,
                              hipStream_t stream) {
  const float* cls  = (const float*)d_in[0];
  const float* bbox = (const float*)d_in[1];
  const float* gtb  = (const float*)d_in[2];
  const int*   gtl  = (const int*)d_in[3];
  const unsigned char* gmask = (const unsigned char*)d_in[4];

  float* ws = (float*)d_ws;   // 3*NBLK floats, fully overwritten every call

  dim3 grid(BPI, NB_IMG);
  fused_loss_kernel<<<grid, 256, 0, stream>>>(cls, bbox, gtb, gtl, gmask, ws);
  finalize_kernel<<<1, 512, 0, stream>>>(ws, (float*)d_out);
}